// Round 1
// baseline (16846.176 us; speedup 1.0000x reference)
//
#include <hip/hip_runtime.h>

#define T_   2
#define IN_  6
#define DIM_ 36
#define LIN_ 54
#define OUT_ 18
#define BN_EPS 1e-5f

// ---------------------------------------------------------------------------
// Edge scatter: agg[dst] += affine(h[src])   (affine = fused BN of prev layer)
// ---------------------------------------------------------------------------
template<int D, bool AFF>
__global__ __launch_bounds__(256) void scatter_k(
    const float* __restrict__ h, const int* __restrict__ src,
    const int* __restrict__ dst, const float* __restrict__ a,
    const float* __restrict__ b2, float* __restrict__ agg, int ne)
{
    int e = blockIdx.x * 256 + threadIdx.x;
    if (e >= ne) return;
    int s = src[e], d = dst[e];
    const float* hr = h + (long)s * D;
    float*       ar = agg + (long)d * D;
    float v[D];
    if constexpr (D % 4 == 0) {
        #pragma unroll
        for (int k = 0; k < D / 4; ++k) {
            float4 t = reinterpret_cast<const float4*>(hr)[k];
            v[4*k+0] = t.x; v[4*k+1] = t.y; v[4*k+2] = t.z; v[4*k+3] = t.w;
        }
    } else {
        #pragma unroll
        for (int k = 0; k < D / 2; ++k) {
            float2 t = reinterpret_cast<const float2*>(hr)[k];
            v[2*k+0] = t.x; v[2*k+1] = t.y;
        }
    }
    #pragma unroll
    for (int k = 0; k < D; ++k) {
        float x = v[k];
        if constexpr (AFF) x = a[k] * x + b2[k];
        atomicAdd(ar + k, x);
    }
}

// ---------------------------------------------------------------------------
// Node MLP: hin = affine(h) + agg ; y = relu(Wa hin + ba) ;
//           out = relu(Wb y + bb) ; accumulate BN stats (sum, sumsq)
// h and z may alias (each thread touches only its own row).
// ---------------------------------------------------------------------------
template<int DIN, bool AFF>
__global__ __launch_bounds__(256) void node_k(
    const float* h, const float* __restrict__ agg,
    const float* __restrict__ a, const float* __restrict__ b2,
    const float* __restrict__ wa, const float* __restrict__ ba,
    const float* __restrict__ wb, const float* __restrict__ bb,
    float* z, float* __restrict__ stats, int n)
{
    __shared__ float swa[DIM_ * DIN], sba[DIM_], swb[DIM_ * DIM_], sbb[DIM_];
    for (int i = threadIdx.x; i < DIM_ * DIN;  i += 256) swa[i] = wa[i];
    for (int i = threadIdx.x; i < DIM_ * DIM_; i += 256) swb[i] = wb[i];
    if (threadIdx.x < DIM_) { sba[threadIdx.x] = ba[threadIdx.x];
                              sbb[threadIdx.x] = bb[threadIdx.x]; }
    __syncthreads();

    int node = blockIdx.x * 256 + threadIdx.x;
    bool active = node < n;

    float hin[DIN];
    if (active) {
        const float* hr = h   + (long)node * DIN;
        const float* ar = agg + (long)node * DIN;
        #pragma unroll
        for (int k = 0; k < DIN; ++k) {
            float x = hr[k];
            if constexpr (AFF) x = a[k] * x + b2[k];
            hin[k] = x + ar[k];
        }
    } else {
        #pragma unroll
        for (int k = 0; k < DIN; ++k) hin[k] = 0.f;
    }

    float y[DIM_];
    #pragma unroll
    for (int j = 0; j < DIM_; ++j) {
        float acc = sba[j];
        #pragma unroll
        for (int k = 0; k < DIN; ++k) acc = fmaf(swa[j * DIN + k], hin[k], acc);
        y[j] = fmaxf(acc, 0.f);
    }

    float out[DIM_];
    #pragma unroll
    for (int j = 0; j < DIM_; ++j) {
        float acc = sbb[j];
        #pragma unroll
        for (int k = 0; k < DIM_; ++k) acc = fmaf(swb[j * DIM_ + k], y[k], acc);
        float o = fmaxf(acc, 0.f);
        out[j] = active ? o : 0.f;
    }

    if (active) {
        float* zr = z + (long)node * DIM_;
        #pragma unroll
        for (int j = 0; j < DIM_ / 4; ++j) {
            float4 t; t.x = out[4*j]; t.y = out[4*j+1]; t.z = out[4*j+2]; t.w = out[4*j+3];
            reinterpret_cast<float4*>(zr)[j] = t;
        }
    }

    // BN stats: wave-level shuffle reduce, one atomic pair per wave per feature
    #pragma unroll
    for (int j = 0; j < DIM_; ++j) {
        float s = out[j], sq = out[j] * out[j];
        for (int off = 32; off; off >>= 1) {
            s  += __shfl_down(s,  off);
            sq += __shfl_down(sq, off);
        }
        if ((threadIdx.x & 63) == 0) {
            atomicAdd(&stats[j], s);
            atomicAdd(&stats[DIM_ + j], sq);
        }
    }
}

// ---------------------------------------------------------------------------
// BN finalize -> fused affine coefficients a, b2
// ---------------------------------------------------------------------------
__global__ void bnfin_k(const float* __restrict__ stats, const float* __restrict__ g,
                        const float* __restrict__ b, float* __restrict__ a,
                        float* __restrict__ b2, float inv_n)
{
    int f = threadIdx.x;
    if (f < DIM_) {
        float mean = stats[f] * inv_n;
        float var  = stats[DIM_ + f] * inv_n - mean * mean;
        float aa   = g[f] / sqrtf(var + BN_EPS);
        a[f]  = aa;
        b2[f] = b[f] - aa * mean;
    }
}

// ---------------------------------------------------------------------------
// Per-graph mean pool (batch sorted): one block per graph, binary-search bounds
// ---------------------------------------------------------------------------
__global__ __launch_bounds__(288) void pool_k(
    const float* __restrict__ z, const float* __restrict__ a,
    const float* __restrict__ b2, const int* __restrict__ batch,
    float* __restrict__ emb, int col0, int n)
{
    int g = blockIdx.x;
    __shared__ int slo, shi;
    if (threadIdx.x == 0) {
        int lo = 0, hi = n;
        while (lo < hi) { int m = (lo + hi) >> 1; if (batch[m] < g) lo = m + 1; else hi = m; }
        slo = lo;
        int lo2 = lo, hi2 = n;
        while (lo2 < hi2) { int m = (lo2 + hi2) >> 1; if (batch[m] < g + 1) lo2 = m + 1; else hi2 = m; }
        shi = lo2;
    }
    __syncthreads();
    int lo = slo, hi = shi;
    int f = threadIdx.x % DIM_, j = threadIdx.x / DIM_;   // j in 0..7
    float acc = 0.f;
    for (int i = lo + j; i < hi; i += 8) acc += z[(long)i * DIM_ + f];
    __shared__ float sred[288];
    sred[threadIdx.x] = acc;
    __syncthreads();
    if (threadIdx.x < DIM_) {
        float s = 0.f;
        #pragma unroll
        for (int jj = 0; jj < 8; ++jj) s += sred[f + DIM_ * jj];
        int cnt = hi - lo;
        float val = 0.f;
        if (cnt > 0) val = a[f] * (s / (float)cnt) + b2[f];
        emb[(long)g * (T_ * DIM_) + col0 + f] = val;
    }
}

// ---------------------------------------------------------------------------
// Head: 72 -> 54 relu -> 18 relu -> 1 sigmoid, one thread per graph
// ---------------------------------------------------------------------------
__global__ __launch_bounds__(256) void head_k(
    const float* __restrict__ emb,
    const float* __restrict__ hw1, const float* __restrict__ hb1,
    const float* __restrict__ hw2, const float* __restrict__ hb2,
    const float* __restrict__ hw3, const float* __restrict__ hb3,
    float* __restrict__ out, int ng)
{
    const int EMB = T_ * DIM_;            // 72
    __shared__ float s1[LIN_ * EMB], sb1[LIN_], s2[OUT_ * LIN_], sb2[OUT_], s3[OUT_];
    __shared__ float sb3;
    for (int i = threadIdx.x; i < LIN_ * EMB;  i += 256) s1[i] = hw1[i];
    for (int i = threadIdx.x; i < OUT_ * LIN_; i += 256) s2[i] = hw2[i];
    if (threadIdx.x < LIN_) sb1[threadIdx.x] = hb1[threadIdx.x];
    if (threadIdx.x < OUT_) { sb2[threadIdx.x] = hb2[threadIdx.x];
                              s3[threadIdx.x]  = hw3[threadIdx.x]; }
    if (threadIdx.x == 0) sb3 = hb3[0];
    __syncthreads();

    int g = blockIdx.x * 256 + threadIdx.x;
    if (g >= ng) return;

    float e[EMB];
    #pragma unroll
    for (int k = 0; k < EMB; ++k) e[k] = emb[(long)g * EMB + k];

    float t1[LIN_];
    #pragma unroll
    for (int j = 0; j < LIN_; ++j) {
        float acc = sb1[j];
        #pragma unroll
        for (int k = 0; k < EMB; ++k) acc = fmaf(s1[j * EMB + k], e[k], acc);
        t1[j] = fmaxf(acc, 0.f);
    }
    float t2[OUT_];
    #pragma unroll
    for (int j = 0; j < OUT_; ++j) {
        float acc = sb2[j];
        #pragma unroll
        for (int k = 0; k < LIN_; ++k) acc = fmaf(s2[j * LIN_ + k], t1[k], acc);
        t2[j] = fmaxf(acc, 0.f);
    }
    float acc = sb3;
    #pragma unroll
    for (int k = 0; k < OUT_; ++k) acc = fmaf(s3[k], t2[k], acc);
    out[g] = 1.f / (1.f + expf(-acc));
}

// ---------------------------------------------------------------------------
extern "C" void kernel_launch(void* const* d_in, const int* in_sizes, int n_in,
                              void* d_out, int out_size, void* d_ws, size_t ws_size,
                              hipStream_t stream)
{
    const float* x     = (const float*)d_in[0];
    const int*   ei    = (const int*)d_in[1];
    const int*   batch = (const int*)d_in[2];
    const float* wA[3] = {(const float*)d_in[3], (const float*)d_in[7], (const float*)d_in[11]};
    const float* bA[3] = {(const float*)d_in[4], (const float*)d_in[8], (const float*)d_in[12]};
    const float* wB[3] = {(const float*)d_in[5], (const float*)d_in[9], (const float*)d_in[13]};
    const float* bB[3] = {(const float*)d_in[6], (const float*)d_in[10], (const float*)d_in[14]};
    const float* bng = (const float*)d_in[15];
    const float* bnb = (const float*)d_in[16];
    const float* hw1 = (const float*)d_in[17];
    const float* hb1 = (const float*)d_in[18];
    const float* hw2 = (const float*)d_in[19];
    const float* hb2 = (const float*)d_in[20];
    const float* hw3 = (const float*)d_in[21];
    const float* hb3 = (const float*)d_in[22];

    const int N = in_sizes[2] / T_;           // nodes
    const int E = in_sizes[1] / (2 * T_);     // edges per transform
    const int G = out_size;                   // graphs

    const size_t bufN = (size_t)N * DIM_;     // floats per node buffer
    char* ws = (char*)d_ws;
    float* agg    = (float*)ws;               // N*36
    float* zA     = agg + bufN;               // N*36
    // ping-pong z if workspace allows, else safe in-place (node_k h/z not restrict)
    size_t need_pp = (3 * bufN + 256 + (size_t)G * T_ * DIM_) * sizeof(float);
    float* zB     = (ws_size >= need_pp) ? (zA + bufN) : zA;
    float* tail   = (ws_size >= need_pp) ? (zB + bufN) : (zA + bufN);
    float* stats  = tail;                     // 72
    float* acoef  = stats + 2 * DIM_;         // 36
    float* b2coef = acoef + DIM_;             // 36
    float* emb    = b2coef + DIM_;            // G*72

    float* outp = (float*)d_out;

    const int gsc = (E + 255) / 256;
    const int gn  = (N + 255) / 256;

    for (int t = 0; t < T_; ++t) {
        const int*   srcp = ei + (size_t)t * 2 * E;
        const int*   dstp = srcp + E;
        const float* xt   = x + (size_t)t * N * IN_;

        // z rotation: c0 -> zA ; c1: zA -> zB ; c2: zB -> zA ; pool reads zA
        for (int c = 0; c < 3; ++c) {
            const float* zin  = (c == 1) ? zA : zB;   // only used for c>0
            float*       zout = (c == 1) ? zB : zA;
            int din = (c == 0) ? IN_ : DIM_;

            hipMemsetAsync(agg, 0, (size_t)N * din * sizeof(float), stream);
            if (c == 0)
                scatter_k<IN_, false><<<gsc, 256, 0, stream>>>(xt, srcp, dstp,
                        nullptr, nullptr, agg, E);
            else
                scatter_k<DIM_, true><<<gsc, 256, 0, stream>>>(zin, srcp, dstp,
                        acoef, b2coef, agg, E);

            hipMemsetAsync(stats, 0, 2 * DIM_ * sizeof(float), stream);

            const float* wa = wA[c] + (size_t)t * DIM_ * din;
            const float* ba = bA[c] + (size_t)t * DIM_;
            const float* wb = wB[c] + (size_t)t * DIM_ * DIM_;
            const float* bb = bB[c] + (size_t)t * DIM_;
            if (c == 0)
                node_k<IN_, false><<<gn, 256, 0, stream>>>(xt, agg, nullptr, nullptr,
                        wa, ba, wb, bb, zout, stats, N);
            else
                node_k<DIM_, true><<<gn, 256, 0, stream>>>(zin, agg, acoef, b2coef,
                        wa, ba, wb, bb, zout, stats, N);

            bnfin_k<<<1, 64, 0, stream>>>(stats,
                    bng + ((size_t)t * 3 + c) * DIM_,
                    bnb + ((size_t)t * 3 + c) * DIM_,
                    acoef, b2coef, 1.0f / (float)N);
        }
        pool_k<<<G, 288, 0, stream>>>(zA, acoef, b2coef, batch + (size_t)t * N,
                                      emb, t * DIM_, N);
    }
    head_k<<<(G + 255) / 256, 256, 0, stream>>>(emb, hw1, hb1, hw2, hb2, hw3, hb3,
                                                outp, G);
}

// Round 2
// 4679.409 us; speedup vs baseline: 3.6001x; 3.6001x over previous
//
#include <hip/hip_runtime.h>

#define T_   2
#define IN_  6
#define DIM_ 36
#define LIN_ 54
#define OUT_ 18
#define BN_EPS 1e-5f

// ===========================================================================
// CSR build (counting sort by dst)
// ===========================================================================
__global__ __launch_bounds__(256) void degcnt_k(const int* __restrict__ dst,
                                                int* __restrict__ deg, int ne)
{
    int e = blockIdx.x * 256 + threadIdx.x;
    if (e < ne) atomicAdd(&deg[dst[e]], 1);
}

__global__ __launch_bounds__(256) void partsum_k(const int* __restrict__ deg,
                                                 int* __restrict__ part, int n)
{
    __shared__ int s[256];
    int i = blockIdx.x * 256 + threadIdx.x;
    s[threadIdx.x] = (i < n) ? deg[i] : 0;
    __syncthreads();
    for (int off = 128; off; off >>= 1) {
        if (threadIdx.x < off) s[threadIdx.x] += s[threadIdx.x + off];
        __syncthreads();
    }
    if (threadIdx.x == 0) part[blockIdx.x] = s[0];
}

__global__ __launch_bounds__(1024) void scanpart_k(int* part, int nb)
{
    __shared__ int s[1024];
    int v = (threadIdx.x < nb) ? part[threadIdx.x] : 0;
    s[threadIdx.x] = v;
    __syncthreads();
    for (int off = 1; off < 1024; off <<= 1) {
        int t = (threadIdx.x >= off) ? s[threadIdx.x - off] : 0;
        __syncthreads();
        s[threadIdx.x] += t;
        __syncthreads();
    }
    if (threadIdx.x < nb) part[threadIdx.x] = s[threadIdx.x];
}

__global__ __launch_bounds__(256) void scanchunk_k(const int* __restrict__ deg,
        const int* __restrict__ part, int* __restrict__ rp,
        int* __restrict__ cur, int n)
{
    __shared__ int s[256];
    int i = blockIdx.x * 256 + threadIdx.x;
    int v = (i < n) ? deg[i] : 0;
    s[threadIdx.x] = v;
    __syncthreads();
    for (int off = 1; off < 256; off <<= 1) {
        int t = (threadIdx.x >= off) ? s[threadIdx.x - off] : 0;
        __syncthreads();
        s[threadIdx.x] += t;
        __syncthreads();
    }
    int off0 = blockIdx.x ? part[blockIdx.x - 1] : 0;
    if (i < n) {
        int incl = s[threadIdx.x];
        int excl = off0 + incl - v;
        rp[i] = excl;
        cur[i] = excl;
        if (i == n - 1) rp[n] = off0 + incl;
    }
}

__global__ __launch_bounds__(256) void fill_k(const int* __restrict__ src,
        const int* __restrict__ dst, int* __restrict__ cur,
        int* __restrict__ csr, int ne)
{
    int e = blockIdx.x * 256 + threadIdx.x;
    if (e < ne) {
        int p = atomicAdd(&cur[dst[e]], 1);
        csr[p] = src[e];
    }
}

// ===========================================================================
// CSR gather: agg[i] = sum_{j in N(i)} h[j]   (RAW sums, no affine — linear)
// D lanes per node, feature-per-lane.
// ===========================================================================
template<int D>
__global__ __launch_bounds__(576) void gather_k(const float* __restrict__ h,
        const int* __restrict__ rp, const int* __restrict__ csr,
        float* __restrict__ agg, int n)
{
    const int NPB = 576 / D;
    int g = blockIdx.x * NPB + threadIdx.x / D;
    int lane = threadIdx.x % D;
    if (g >= n) return;
    int lo = rp[g], hi = rp[g + 1];
    float acc0 = 0.f, acc1 = 0.f;
    int e = lo;
    for (; e + 1 < hi; e += 2) {
        int s0 = csr[e], s1 = csr[e + 1];
        acc0 += h[(long)s0 * D + lane];
        acc1 += h[(long)s1 * D + lane];
    }
    if (e < hi) acc0 += h[(long)csr[e] * D + lane];
    agg[(long)g * D + lane] = acc0 + acc1;
}

// ===========================================================================
// Fallback scatter (raw sums, atomics) — only if ws too small for CSR
// ===========================================================================
template<int D>
__global__ __launch_bounds__(256) void scatter_raw_k(const float* __restrict__ h,
        const int* __restrict__ src, const int* __restrict__ dst,
        float* __restrict__ agg, int ne)
{
    int e = blockIdx.x * 256 + threadIdx.x;
    if (e >= ne) return;
    int s = src[e], d = dst[e];
    const float* hr = h + (long)s * D;
    float* ar = agg + (long)d * D;
    #pragma unroll
    for (int k = 0; k < D; ++k) atomicAdd(ar + k, hr[k]);
}

// ===========================================================================
// Node MLP: hin = a⊙(h_i + S_i) + (1+deg)·b2  (fused BN of prev layer)
//           y = relu(Wa hin + ba) ; out = relu(Wb y + bb) ; BN stats
// h and z may alias (each thread touches only its own row).
// ===========================================================================
template<int DIN, bool AFF>
__global__ __launch_bounds__(256) void node_k(
    const float* h, const float* __restrict__ agg, const int* __restrict__ deg,
    const float* __restrict__ a, const float* __restrict__ b2,
    const float* __restrict__ wa, const float* __restrict__ ba,
    const float* __restrict__ wb, const float* __restrict__ bb,
    float* z, float* __restrict__ stats, int n)
{
    __shared__ float swa[DIM_ * DIN], sba[DIM_], swb[DIM_ * DIM_], sbb[DIM_];
    for (int i = threadIdx.x; i < DIM_ * DIN;  i += 256) swa[i] = wa[i];
    for (int i = threadIdx.x; i < DIM_ * DIM_; i += 256) swb[i] = wb[i];
    if (threadIdx.x < DIM_) { sba[threadIdx.x] = ba[threadIdx.x];
                              sbb[threadIdx.x] = bb[threadIdx.x]; }
    __syncthreads();

    int node = blockIdx.x * 256 + threadIdx.x;
    bool active = node < n;

    float hin[DIN];
    if (active) {
        const float* hr = h   + (long)node * DIN;
        const float* ar = agg + (long)node * DIN;
        float ds = 0.f;
        if constexpr (AFF) ds = 1.0f + (float)deg[node];
        #pragma unroll
        for (int k = 0; k < DIN; ++k) {
            float x = hr[k] + ar[k];
            if constexpr (AFF) x = a[k] * x + ds * b2[k];
            hin[k] = x;
        }
    } else {
        #pragma unroll
        for (int k = 0; k < DIN; ++k) hin[k] = 0.f;
    }

    float y[DIM_];
    #pragma unroll
    for (int j = 0; j < DIM_; ++j) {
        float acc = sba[j];
        #pragma unroll
        for (int k = 0; k < DIN; ++k) acc = fmaf(swa[j * DIN + k], hin[k], acc);
        y[j] = fmaxf(acc, 0.f);
    }

    float out[DIM_];
    #pragma unroll
    for (int j = 0; j < DIM_; ++j) {
        float acc = sbb[j];
        #pragma unroll
        for (int k = 0; k < DIM_; ++k) acc = fmaf(swb[j * DIM_ + k], y[k], acc);
        float o = fmaxf(acc, 0.f);
        out[j] = active ? o : 0.f;
    }

    if (active) {
        float* zr = z + (long)node * DIM_;
        #pragma unroll
        for (int j = 0; j < DIM_ / 4; ++j) {
            float4 t; t.x = out[4*j]; t.y = out[4*j+1]; t.z = out[4*j+2]; t.w = out[4*j+3];
            reinterpret_cast<float4*>(zr)[j] = t;
        }
    }

    // BN stats: wave shuffle reduce, one atomic pair per wave per feature
    #pragma unroll
    for (int j = 0; j < DIM_; ++j) {
        float s = out[j], sq = out[j] * out[j];
        for (int off = 32; off; off >>= 1) {
            s  += __shfl_down(s,  off);
            sq += __shfl_down(sq, off);
        }
        if ((threadIdx.x & 63) == 0) {
            atomicAdd(&stats[j], s);
            atomicAdd(&stats[DIM_ + j], sq);
        }
    }
}

// ===========================================================================
// BN finalize -> fused affine coefficients a, b2
// ===========================================================================
__global__ void bnfin_k(const float* __restrict__ stats, const float* __restrict__ g,
                        const float* __restrict__ b, float* __restrict__ a,
                        float* __restrict__ b2, float inv_n)
{
    int f = threadIdx.x;
    if (f < DIM_) {
        float mean = stats[f] * inv_n;
        float var  = stats[DIM_ + f] * inv_n - mean * mean;
        float aa   = g[f] / sqrtf(var + BN_EPS);
        a[f]  = aa;
        b2[f] = b[f] - aa * mean;
    }
}

// ===========================================================================
// Per-graph mean pool (batch sorted): one block per graph, binary search
// ===========================================================================
__global__ __launch_bounds__(288) void pool_k(
    const float* __restrict__ z, const float* __restrict__ a,
    const float* __restrict__ b2, const int* __restrict__ batch,
    float* __restrict__ emb, int col0, int n)
{
    int g = blockIdx.x;
    __shared__ int slo, shi;
    if (threadIdx.x == 0) {
        int lo = 0, hi = n;
        while (lo < hi) { int m = (lo + hi) >> 1; if (batch[m] < g) lo = m + 1; else hi = m; }
        slo = lo;
        int lo2 = lo, hi2 = n;
        while (lo2 < hi2) { int m = (lo2 + hi2) >> 1; if (batch[m] < g + 1) lo2 = m + 1; else hi2 = m; }
        shi = lo2;
    }
    __syncthreads();
    int lo = slo, hi = shi;
    int f = threadIdx.x % DIM_, j = threadIdx.x / DIM_;   // j in 0..7
    float acc = 0.f;
    for (int i = lo + j; i < hi; i += 8) acc += z[(long)i * DIM_ + f];
    __shared__ float sred[288];
    sred[threadIdx.x] = acc;
    __syncthreads();
    if (threadIdx.x < DIM_) {
        float s = 0.f;
        #pragma unroll
        for (int jj = 0; jj < 8; ++jj) s += sred[f + DIM_ * jj];
        int cnt = hi - lo;
        float val = 0.f;
        if (cnt > 0) val = a[f] * (s / (float)cnt) + b2[f];
        emb[(long)g * (T_ * DIM_) + col0 + f] = val;
    }
}

// ===========================================================================
// Head: 72 -> 54 relu -> 18 relu -> 1 sigmoid, one thread per graph
// ===========================================================================
__global__ __launch_bounds__(256) void head_k(
    const float* __restrict__ emb,
    const float* __restrict__ hw1, const float* __restrict__ hb1,
    const float* __restrict__ hw2, const float* __restrict__ hb2,
    const float* __restrict__ hw3, const float* __restrict__ hb3,
    float* __restrict__ out, int ng)
{
    const int EMB = T_ * DIM_;            // 72
    __shared__ float s1[LIN_ * EMB], sb1[LIN_], s2[OUT_ * LIN_], sb2[OUT_], s3[OUT_];
    __shared__ float sb3;
    for (int i = threadIdx.x; i < LIN_ * EMB;  i += 256) s1[i] = hw1[i];
    for (int i = threadIdx.x; i < OUT_ * LIN_; i += 256) s2[i] = hw2[i];
    if (threadIdx.x < LIN_) sb1[threadIdx.x] = hb1[threadIdx.x];
    if (threadIdx.x < OUT_) { sb2[threadIdx.x] = hb2[threadIdx.x];
                              s3[threadIdx.x]  = hw3[threadIdx.x]; }
    if (threadIdx.x == 0) sb3 = hb3[0];
    __syncthreads();

    int g = blockIdx.x * 256 + threadIdx.x;
    if (g >= ng) return;

    float e[EMB];
    #pragma unroll
    for (int k = 0; k < EMB; ++k) e[k] = emb[(long)g * EMB + k];

    float t1[LIN_];
    #pragma unroll
    for (int j = 0; j < LIN_; ++j) {
        float acc = sb1[j];
        #pragma unroll
        for (int k = 0; k < EMB; ++k) acc = fmaf(s1[j * EMB + k], e[k], acc);
        t1[j] = fmaxf(acc, 0.f);
    }
    float t2[OUT_];
    #pragma unroll
    for (int j = 0; j < OUT_; ++j) {
        float acc = sb2[j];
        #pragma unroll
        for (int k = 0; k < LIN_; ++k) acc = fmaf(s2[j * LIN_ + k], t1[k], acc);
        t2[j] = fmaxf(acc, 0.f);
    }
    float acc = sb3;
    #pragma unroll
    for (int k = 0; k < OUT_; ++k) acc = fmaf(s3[k], t2[k], acc);
    out[g] = 1.f / (1.f + expf(-acc));
}

// ===========================================================================
extern "C" void kernel_launch(void* const* d_in, const int* in_sizes, int n_in,
                              void* d_out, int out_size, void* d_ws, size_t ws_size,
                              hipStream_t stream)
{
    const float* x     = (const float*)d_in[0];
    const int*   ei    = (const int*)d_in[1];
    const int*   batch = (const int*)d_in[2];
    const float* wA[3] = {(const float*)d_in[3], (const float*)d_in[7], (const float*)d_in[11]};
    const float* bA[3] = {(const float*)d_in[4], (const float*)d_in[8], (const float*)d_in[12]};
    const float* wB[3] = {(const float*)d_in[5], (const float*)d_in[9], (const float*)d_in[13]};
    const float* bB[3] = {(const float*)d_in[6], (const float*)d_in[10], (const float*)d_in[14]};
    const float* bng = (const float*)d_in[15];
    const float* bnb = (const float*)d_in[16];
    const float* hw1 = (const float*)d_in[17];
    const float* hb1 = (const float*)d_in[18];
    const float* hw2 = (const float*)d_in[19];
    const float* hb2 = (const float*)d_in[20];
    const float* hw3 = (const float*)d_in[21];
    const float* hb3 = (const float*)d_in[22];

    const int N = in_sizes[2] / T_;           // nodes
    const int E = in_sizes[1] / (2 * T_);     // edges per transform
    const int G = out_size;                   // graphs

    // ---- workspace layout -------------------------------------------------
    const size_t bufN = (size_t)N * DIM_;
    const size_t tailF = 2 * DIM_ + DIM_ + DIM_ + (size_t)G * T_ * DIM_;
    char* ws = (char*)d_ws;
    float* agg    = (float*)ws;               // N*36
    float* z      = agg + bufN;               // N*36
    float* stats  = z + bufN;                 // 72
    float* acoef  = stats + 2 * DIM_;         // 36
    float* b2coef = acoef + DIM_;             // 36
    float* emb    = b2coef + DIM_;            // G*72
    int*   ideg   = (int*)(emb + (size_t)G * T_ * DIM_);  // N
    int*   irp    = ideg + N;                 // N+1
    int*   icur   = irp + N + 1;              // N+1
    int*   icsr   = icur + N + 1;             // E
    int*   ipart  = icsr + E;                 // <=1024

    const int NB = (N + 255) / 256;           // scan chunks
    size_t need_csr = (2 * bufN + tailF) * sizeof(float)
                    + ((size_t)N + 2 * (N + 1) + E + 1024) * sizeof(int);
    bool use_csr = (ws_size >= need_csr) && (NB <= 1024);

    float* outp = (float*)d_out;
    const int gsc = (E + 255) / 256;
    const int gn  = (N + 255) / 256;

    for (int t = 0; t < T_; ++t) {
        const int*   srcp = ei + (size_t)t * 2 * E;
        const int*   dstp = srcp + E;
        const float* xt   = x + (size_t)t * N * IN_;

        // ---- degree count (both paths need deg) ----
        hipMemsetAsync(ideg, 0, (size_t)N * sizeof(int), stream);
        degcnt_k<<<gsc, 256, 0, stream>>>(dstp, ideg, E);

        if (use_csr) {
            partsum_k<<<NB, 256, 0, stream>>>(ideg, ipart, N);
            scanpart_k<<<1, 1024, 0, stream>>>(ipart, NB);
            scanchunk_k<<<NB, 256, 0, stream>>>(ideg, ipart, irp, icur, N);
            fill_k<<<gsc, 256, 0, stream>>>(srcp, dstp, icur, icsr, E);
        }

        for (int c = 0; c < 3; ++c) {
            int din = (c == 0) ? IN_ : DIM_;
            const float* hin = (c == 0) ? xt : z;

            if (use_csr) {
                if (c == 0)
                    gather_k<IN_><<<(N + 95) / 96, 576, 0, stream>>>(xt, irp, icsr, agg, N);
                else
                    gather_k<DIM_><<<(N + 15) / 16, 576, 0, stream>>>(z, irp, icsr, agg, N);
            } else {
                hipMemsetAsync(agg, 0, (size_t)N * din * sizeof(float), stream);
                if (c == 0)
                    scatter_raw_k<IN_><<<gsc, 256, 0, stream>>>(xt, srcp, dstp, agg, E);
                else
                    scatter_raw_k<DIM_><<<gsc, 256, 0, stream>>>(z, srcp, dstp, agg, E);
            }

            hipMemsetAsync(stats, 0, 2 * DIM_ * sizeof(float), stream);

            const float* wa = wA[c] + (size_t)t * DIM_ * din;
            const float* ba = bA[c] + (size_t)t * DIM_;
            const float* wb = wB[c] + (size_t)t * DIM_ * DIM_;
            const float* bb = bB[c] + (size_t)t * DIM_;
            if (c == 0)
                node_k<IN_, false><<<gn, 256, 0, stream>>>(xt, agg, ideg, nullptr, nullptr,
                        wa, ba, wb, bb, z, stats, N);
            else
                node_k<DIM_, true><<<gn, 256, 0, stream>>>(z, agg, ideg, acoef, b2coef,
                        wa, ba, wb, bb, z, stats, N);

            bnfin_k<<<1, 64, 0, stream>>>(stats,
                    bng + ((size_t)t * 3 + c) * DIM_,
                    bnb + ((size_t)t * 3 + c) * DIM_,
                    acoef, b2coef, 1.0f / (float)N);
        }
        pool_k<<<G, 288, 0, stream>>>(z, acoef, b2coef, batch + (size_t)t * N,
                                      emb, t * DIM_, N);
    }
    head_k<<<(G + 255) / 256, 256, 0, stream>>>(emb, hw1, hb1, hw2, hb2, hw3, hb3,
                                                outp, G);
}

// Round 3
// 1654.363 us; speedup vs baseline: 10.1829x; 2.8285x over previous
//
#include <hip/hip_runtime.h>

#define T_   2
#define IN_  6
#define DIM_ 36
#define LIN_ 54
#define OUT_ 18
#define BN_EPS 1e-5f

// ===========================================================================
// CSR build (counting sort by dst)
// ===========================================================================
__global__ __launch_bounds__(256) void degcnt_k(const int* __restrict__ dst,
                                                int* __restrict__ deg, int ne)
{
    int e = blockIdx.x * 256 + threadIdx.x;
    if (e < ne) atomicAdd(&deg[dst[e]], 1);
}

__global__ __launch_bounds__(256) void partsum_k(const int* __restrict__ deg,
                                                 int* __restrict__ part, int n)
{
    __shared__ int s[256];
    int i = blockIdx.x * 256 + threadIdx.x;
    s[threadIdx.x] = (i < n) ? deg[i] : 0;
    __syncthreads();
    for (int off = 128; off; off >>= 1) {
        if (threadIdx.x < off) s[threadIdx.x] += s[threadIdx.x + off];
        __syncthreads();
    }
    if (threadIdx.x == 0) part[blockIdx.x] = s[0];
}

__global__ __launch_bounds__(1024) void scanpart_k(int* part, int nb)
{
    __shared__ int s[1024];
    int v = (threadIdx.x < nb) ? part[threadIdx.x] : 0;
    s[threadIdx.x] = v;
    __syncthreads();
    for (int off = 1; off < 1024; off <<= 1) {
        int t = (threadIdx.x >= off) ? s[threadIdx.x - off] : 0;
        __syncthreads();
        s[threadIdx.x] += t;
        __syncthreads();
    }
    if (threadIdx.x < nb) part[threadIdx.x] = s[threadIdx.x];
}

__global__ __launch_bounds__(256) void scanchunk_k(const int* __restrict__ deg,
        const int* __restrict__ part, int* __restrict__ rp,
        int* __restrict__ cur, int n)
{
    __shared__ int s[256];
    int i = blockIdx.x * 256 + threadIdx.x;
    int v = (i < n) ? deg[i] : 0;
    s[threadIdx.x] = v;
    __syncthreads();
    for (int off = 1; off < 256; off <<= 1) {
        int t = (threadIdx.x >= off) ? s[threadIdx.x - off] : 0;
        __syncthreads();
        s[threadIdx.x] += t;
        __syncthreads();
    }
    int off0 = blockIdx.x ? part[blockIdx.x - 1] : 0;
    if (i < n) {
        int incl = s[threadIdx.x];
        int excl = off0 + incl - v;
        rp[i] = excl;
        cur[i] = excl;
        if (i == n - 1) rp[n] = off0 + incl;
    }
}

__global__ __launch_bounds__(256) void fill_k(const int* __restrict__ src,
        const int* __restrict__ dst, int* __restrict__ cur,
        int* __restrict__ csr, int ne)
{
    int e = blockIdx.x * 256 + threadIdx.x;
    if (e < ne) {
        int p = atomicAdd(&cur[dst[e]], 1);
        csr[p] = src[e];
    }
}

// ===========================================================================
// CSR gather: agg[i] = sum_{j in N(i)} h[j]   (RAW sums, no affine — linear)
// ===========================================================================
template<int D>
__global__ __launch_bounds__(576) void gather_k(const float* __restrict__ h,
        const int* __restrict__ rp, const int* __restrict__ csr,
        float* __restrict__ agg, int n)
{
    const int NPB = 576 / D;
    int g = blockIdx.x * NPB + threadIdx.x / D;
    int lane = threadIdx.x % D;
    if (g >= n) return;
    int lo = rp[g], hi = rp[g + 1];
    float acc0 = 0.f, acc1 = 0.f;
    int e = lo;
    for (; e + 1 < hi; e += 2) {
        int s0 = csr[e], s1 = csr[e + 1];
        acc0 += h[(long)s0 * D + lane];
        acc1 += h[(long)s1 * D + lane];
    }
    if (e < hi) acc0 += h[(long)csr[e] * D + lane];
    agg[(long)g * D + lane] = acc0 + acc1;
}

// ===========================================================================
// Fallback scatter (raw sums, atomics) — only if ws too small for CSR
// ===========================================================================
template<int D>
__global__ __launch_bounds__(256) void scatter_raw_k(const float* __restrict__ h,
        const int* __restrict__ src, const int* __restrict__ dst,
        float* __restrict__ agg, int ne)
{
    int e = blockIdx.x * 256 + threadIdx.x;
    if (e >= ne) return;
    int s = src[e], d = dst[e];
    const float* hr = h + (long)s * D;
    float* ar = agg + (long)d * D;
    #pragma unroll
    for (int k = 0; k < D; ++k) atomicAdd(ar + k, hr[k]);
}

// ===========================================================================
// Node MLP: hin = a⊙(h_i + S_i) + (1+deg)·b2  (fused BN of prev layer)
//           y = relu(Wa hin + ba) ; out = relu(Wb y + bb)
// BN stats -> per-block partial row (NO contended global atomics: the R2
// version's 112K atomicAdds onto 72 words serialized one L2 slice, 660us).
// h and z may alias (each thread touches only its own row).
// ===========================================================================
template<int DIN, bool AFF>
__global__ __launch_bounds__(256) void node_k(
    const float* h, const float* __restrict__ agg, const int* __restrict__ deg,
    const float* __restrict__ a, const float* __restrict__ b2,
    const float* __restrict__ wa, const float* __restrict__ ba,
    const float* __restrict__ wb, const float* __restrict__ bb,
    float* z, float* __restrict__ bstats, int n)
{
    __shared__ float swa[DIM_ * DIN], sba[DIM_], swb[DIM_ * DIM_], sbb[DIM_];
    __shared__ float sstat[4][2 * DIM_];
    for (int i = threadIdx.x; i < DIM_ * DIN;  i += 256) swa[i] = wa[i];
    for (int i = threadIdx.x; i < DIM_ * DIM_; i += 256) swb[i] = wb[i];
    if (threadIdx.x < DIM_) { sba[threadIdx.x] = ba[threadIdx.x];
                              sbb[threadIdx.x] = bb[threadIdx.x]; }
    __syncthreads();

    int node = blockIdx.x * 256 + threadIdx.x;
    bool active = node < n;

    float hin[DIN];
    if (active) {
        const float* hr = h   + (long)node * DIN;
        const float* ar = agg + (long)node * DIN;
        float ds = 0.f;
        if constexpr (AFF) ds = 1.0f + (float)deg[node];
        #pragma unroll
        for (int k = 0; k < DIN; ++k) {
            float x = hr[k] + ar[k];
            if constexpr (AFF) x = a[k] * x + ds * b2[k];
            hin[k] = x;
        }
    } else {
        #pragma unroll
        for (int k = 0; k < DIN; ++k) hin[k] = 0.f;
    }

    float y[DIM_];
    #pragma unroll
    for (int j = 0; j < DIM_; ++j) {
        float acc = sba[j];
        #pragma unroll
        for (int k = 0; k < DIN; ++k) acc = fmaf(swa[j * DIN + k], hin[k], acc);
        y[j] = fmaxf(acc, 0.f);
    }

    float out[DIM_];
    #pragma unroll
    for (int j = 0; j < DIM_; ++j) {
        float acc = sbb[j];
        #pragma unroll
        for (int k = 0; k < DIM_; ++k) acc = fmaf(swb[j * DIM_ + k], y[k], acc);
        float o = fmaxf(acc, 0.f);
        out[j] = active ? o : 0.f;
    }

    if (active) {
        float* zr = z + (long)node * DIM_;
        #pragma unroll
        for (int j = 0; j < DIM_ / 4; ++j) {
            float4 t; t.x = out[4*j]; t.y = out[4*j+1]; t.z = out[4*j+2]; t.w = out[4*j+3];
            reinterpret_cast<float4*>(zr)[j] = t;
        }
    }

    // wave shuffle reduce -> LDS -> one partial row per block (plain stores)
    int wid = threadIdx.x >> 6, lane = threadIdx.x & 63;
    #pragma unroll
    for (int j = 0; j < DIM_; ++j) {
        float s = out[j], sq = out[j] * out[j];
        for (int off = 32; off; off >>= 1) {
            s  += __shfl_down(s,  off);
            sq += __shfl_down(sq, off);
        }
        if (lane == 0) { sstat[wid][j] = s; sstat[wid][DIM_ + j] = sq; }
    }
    __syncthreads();
    if (threadIdx.x < 2 * DIM_) {
        float s = sstat[0][threadIdx.x] + sstat[1][threadIdx.x]
                + sstat[2][threadIdx.x] + sstat[3][threadIdx.x];
        bstats[(long)blockIdx.x * (2 * DIM_) + threadIdx.x] = s;
    }
}

// ===========================================================================
// BN reduce over block partials + finalize fused affine coefficients
// ===========================================================================
__global__ __launch_bounds__(128) void bnred_k(const float* __restrict__ bstats,
        int nb, const float* __restrict__ g, const float* __restrict__ b,
        float* __restrict__ a, float* __restrict__ b2, float inv_n)
{
    __shared__ float tot[2 * DIM_];
    int tid = threadIdx.x;
    if (tid < 2 * DIM_) {
        float s = 0.f;
        for (int i = 0; i < nb; ++i) s += bstats[(long)i * (2 * DIM_) + tid];
        tot[tid] = s;
    }
    __syncthreads();
    if (tid < DIM_) {
        float mean = tot[tid] * inv_n;
        float var  = tot[DIM_ + tid] * inv_n - mean * mean;
        float aa   = g[tid] / sqrtf(var + BN_EPS);
        a[tid]  = aa;
        b2[tid] = b[tid] - aa * mean;
    }
}

// ===========================================================================
// Per-graph mean pool (batch sorted): one block per graph, binary search
// ===========================================================================
__global__ __launch_bounds__(288) void pool_k(
    const float* __restrict__ z, const float* __restrict__ a,
    const float* __restrict__ b2, const int* __restrict__ batch,
    float* __restrict__ emb, int col0, int n)
{
    int g = blockIdx.x;
    __shared__ int slo, shi;
    if (threadIdx.x == 0) {
        int lo = 0, hi = n;
        while (lo < hi) { int m = (lo + hi) >> 1; if (batch[m] < g) lo = m + 1; else hi = m; }
        slo = lo;
        int lo2 = lo, hi2 = n;
        while (lo2 < hi2) { int m = (lo2 + hi2) >> 1; if (batch[m] < g + 1) lo2 = m + 1; else hi2 = m; }
        shi = lo2;
    }
    __syncthreads();
    int lo = slo, hi = shi;
    int f = threadIdx.x % DIM_, j = threadIdx.x / DIM_;   // j in 0..7
    float acc = 0.f;
    for (int i = lo + j; i < hi; i += 8) acc += z[(long)i * DIM_ + f];
    __shared__ float sred[288];
    sred[threadIdx.x] = acc;
    __syncthreads();
    if (threadIdx.x < DIM_) {
        float s = 0.f;
        #pragma unroll
        for (int jj = 0; jj < 8; ++jj) s += sred[f + DIM_ * jj];
        int cnt = hi - lo;
        float val = 0.f;
        if (cnt > 0) val = a[f] * (s / (float)cnt) + b2[f];
        emb[(long)g * (T_ * DIM_) + col0 + f] = val;
    }
}

// ===========================================================================
// Head: 72 -> 54 relu -> 18 relu -> 1 sigmoid, one thread per graph
// ===========================================================================
__global__ __launch_bounds__(256) void head_k(
    const float* __restrict__ emb,
    const float* __restrict__ hw1, const float* __restrict__ hb1,
    const float* __restrict__ hw2, const float* __restrict__ hb2,
    const float* __restrict__ hw3, const float* __restrict__ hb3,
    float* __restrict__ out, int ng)
{
    const int EMB = T_ * DIM_;            // 72
    __shared__ float s1[LIN_ * EMB], sb1[LIN_], s2[OUT_ * LIN_], sb2[OUT_], s3[OUT_];
    __shared__ float sb3;
    for (int i = threadIdx.x; i < LIN_ * EMB;  i += 256) s1[i] = hw1[i];
    for (int i = threadIdx.x; i < OUT_ * LIN_; i += 256) s2[i] = hw2[i];
    if (threadIdx.x < LIN_) sb1[threadIdx.x] = hb1[threadIdx.x];
    if (threadIdx.x < OUT_) { sb2[threadIdx.x] = hb2[threadIdx.x];
                              s3[threadIdx.x]  = hw3[threadIdx.x]; }
    if (threadIdx.x == 0) sb3 = hb3[0];
    __syncthreads();

    int g = blockIdx.x * 256 + threadIdx.x;
    if (g >= ng) return;

    float e[EMB];
    #pragma unroll
    for (int k = 0; k < EMB; ++k) e[k] = emb[(long)g * EMB + k];

    float t1[LIN_];
    #pragma unroll
    for (int j = 0; j < LIN_; ++j) {
        float acc = sb1[j];
        #pragma unroll
        for (int k = 0; k < EMB; ++k) acc = fmaf(s1[j * EMB + k], e[k], acc);
        t1[j] = fmaxf(acc, 0.f);
    }
    float t2[OUT_];
    #pragma unroll
    for (int j = 0; j < OUT_; ++j) {
        float acc = sb2[j];
        #pragma unroll
        for (int k = 0; k < LIN_; ++k) acc = fmaf(s2[j * LIN_ + k], t1[k], acc);
        t2[j] = fmaxf(acc, 0.f);
    }
    float acc = sb3;
    #pragma unroll
    for (int k = 0; k < OUT_; ++k) acc = fmaf(s3[k], t2[k], acc);
    out[g] = 1.f / (1.f + expf(-acc));
}

// ===========================================================================
extern "C" void kernel_launch(void* const* d_in, const int* in_sizes, int n_in,
                              void* d_out, int out_size, void* d_ws, size_t ws_size,
                              hipStream_t stream)
{
    const float* x     = (const float*)d_in[0];
    const int*   ei    = (const int*)d_in[1];
    const int*   batch = (const int*)d_in[2];
    const float* wA[3] = {(const float*)d_in[3], (const float*)d_in[7], (const float*)d_in[11]};
    const float* bA[3] = {(const float*)d_in[4], (const float*)d_in[8], (const float*)d_in[12]};
    const float* wB[3] = {(const float*)d_in[5], (const float*)d_in[9], (const float*)d_in[13]};
    const float* bB[3] = {(const float*)d_in[6], (const float*)d_in[10], (const float*)d_in[14]};
    const float* bng = (const float*)d_in[15];
    const float* bnb = (const float*)d_in[16];
    const float* hw1 = (const float*)d_in[17];
    const float* hb1 = (const float*)d_in[18];
    const float* hw2 = (const float*)d_in[19];
    const float* hb2 = (const float*)d_in[20];
    const float* hw3 = (const float*)d_in[21];
    const float* hb3 = (const float*)d_in[22];

    const int N = in_sizes[2] / T_;           // nodes
    const int E = in_sizes[1] / (2 * T_);     // edges per transform
    const int G = out_size;                   // graphs
    const int gn = (N + 255) / 256;           // node_k blocks

    // ---- workspace layout -------------------------------------------------
    const size_t bufN = (size_t)N * DIM_;
    char* ws = (char*)d_ws;
    float* agg    = (float*)ws;               // N*36
    float* z      = agg + bufN;               // N*36
    float* acoef  = z + bufN;                 // 36
    float* b2coef = acoef + DIM_;             // 36
    float* bstats = b2coef + DIM_;            // gn*72
    float* emb    = bstats + (size_t)gn * 2 * DIM_;       // G*72
    int*   ideg   = (int*)(emb + (size_t)G * T_ * DIM_);  // N
    int*   irp    = ideg + N;                 // N+1
    int*   icur   = irp + N + 1;              // N+1
    int*   icsr   = icur + N + 1;             // E
    int*   ipart  = icsr + E;                 // <=1024

    const int NB = (N + 255) / 256;           // scan chunks
    size_t need_csr = (2 * bufN + 2 * DIM_ + (size_t)gn * 2 * DIM_
                       + (size_t)G * T_ * DIM_) * sizeof(float)
                    + ((size_t)N + 2 * (N + 1) + E + 1024) * sizeof(int);
    bool use_csr = (ws_size >= need_csr) && (NB <= 1024);

    float* outp = (float*)d_out;
    const int gsc = (E + 255) / 256;

    for (int t = 0; t < T_; ++t) {
        const int*   srcp = ei + (size_t)t * 2 * E;
        const int*   dstp = srcp + E;
        const float* xt   = x + (size_t)t * N * IN_;

        hipMemsetAsync(ideg, 0, (size_t)N * sizeof(int), stream);
        degcnt_k<<<gsc, 256, 0, stream>>>(dstp, ideg, E);

        if (use_csr) {
            partsum_k<<<NB, 256, 0, stream>>>(ideg, ipart, N);
            scanpart_k<<<1, 1024, 0, stream>>>(ipart, NB);
            scanchunk_k<<<NB, 256, 0, stream>>>(ideg, ipart, irp, icur, N);
            fill_k<<<gsc, 256, 0, stream>>>(srcp, dstp, icur, icsr, E);
        }

        for (int c = 0; c < 3; ++c) {
            int din = (c == 0) ? IN_ : DIM_;

            if (use_csr) {
                if (c == 0)
                    gather_k<IN_><<<(N + 95) / 96, 576, 0, stream>>>(xt, irp, icsr, agg, N);
                else
                    gather_k<DIM_><<<(N + 15) / 16, 576, 0, stream>>>(z, irp, icsr, agg, N);
            } else {
                hipMemsetAsync(agg, 0, (size_t)N * din * sizeof(float), stream);
                if (c == 0)
                    scatter_raw_k<IN_><<<gsc, 256, 0, stream>>>(xt, srcp, dstp, agg, E);
                else
                    scatter_raw_k<DIM_><<<gsc, 256, 0, stream>>>(z, srcp, dstp, agg, E);
            }

            const float* wa = wA[c] + (size_t)t * DIM_ * din;
            const float* ba = bA[c] + (size_t)t * DIM_;
            const float* wb = wB[c] + (size_t)t * DIM_ * DIM_;
            const float* bb = bB[c] + (size_t)t * DIM_;
            if (c == 0)
                node_k<IN_, false><<<gn, 256, 0, stream>>>(xt, agg, ideg, nullptr, nullptr,
                        wa, ba, wb, bb, z, bstats, N);
            else
                node_k<DIM_, true><<<gn, 256, 0, stream>>>(z, agg, ideg, acoef, b2coef,
                        wa, ba, wb, bb, z, bstats, N);

            bnred_k<<<1, 128, 0, stream>>>(bstats, gn,
                    bng + ((size_t)t * 3 + c) * DIM_,
                    bnb + ((size_t)t * 3 + c) * DIM_,
                    acoef, b2coef, 1.0f / (float)N);
        }
        pool_k<<<G, 288, 0, stream>>>(z, acoef, b2coef, batch + (size_t)t * N,
                                      emb, t * DIM_, N);
    }
    head_k<<<(G + 255) / 256, 256, 0, stream>>>(emb, hw1, hb1, hw2, hb2, hw3, hb3,
                                                outp, G);
}

// Round 4
// 1118.701 us; speedup vs baseline: 15.0587x; 1.4788x over previous
//
#include <hip/hip_runtime.h>

#define T_   2
#define IN_  6
#define DIM_ 36
#define LIN_ 54
#define OUT_ 18
#define BN_EPS 1e-5f

// ===========================================================================
// CSR build over tcnt transforms at once (counting sort by dst).
// deg/rp/cur are [tcnt*N]; csr is [tcnt*E] with global positions (t=1 region
// starts at E automatically via the concatenated exclusive scan).
// ===========================================================================
__global__ __launch_bounds__(256) void degcnt_k(const int* __restrict__ ei,
        int* __restrict__ deg, int E, int N, int t0, int tcnt)
{
    int idx = blockIdx.x * 256 + threadIdx.x;
    if (idx >= tcnt * E) return;
    int lt = (idx >= E) ? 1 : 0;            // tcnt <= 2
    int j  = idx - lt * E;
    int tt = t0 + lt;
    int dst = ei[(size_t)tt * 2 * E + E + j];
    atomicAdd(&deg[lt * N + dst], 1);
}

__global__ __launch_bounds__(256) void partsum_k(const int* __restrict__ deg,
                                                 int* __restrict__ part, int n)
{
    __shared__ int s[256];
    int i = blockIdx.x * 256 + threadIdx.x;
    s[threadIdx.x] = (i < n) ? deg[i] : 0;
    __syncthreads();
    for (int off = 128; off; off >>= 1) {
        if (threadIdx.x < off) s[threadIdx.x] += s[threadIdx.x + off];
        __syncthreads();
    }
    if (threadIdx.x == 0) part[blockIdx.x] = s[0];
}

__global__ __launch_bounds__(1024) void scanpart_k(int* part, int nb)
{
    __shared__ int s[1024];
    int v = (threadIdx.x < nb) ? part[threadIdx.x] : 0;
    s[threadIdx.x] = v;
    __syncthreads();
    for (int off = 1; off < 1024; off <<= 1) {
        int t = (threadIdx.x >= off) ? s[threadIdx.x - off] : 0;
        __syncthreads();
        s[threadIdx.x] += t;
        __syncthreads();
    }
    if (threadIdx.x < nb) part[threadIdx.x] = s[threadIdx.x];
}

__global__ __launch_bounds__(256) void scanchunk_k(const int* __restrict__ deg,
        const int* __restrict__ part, int* __restrict__ rp,
        int* __restrict__ cur, int n)
{
    __shared__ int s[256];
    int i = blockIdx.x * 256 + threadIdx.x;
    int v = (i < n) ? deg[i] : 0;
    s[threadIdx.x] = v;
    __syncthreads();
    for (int off = 1; off < 256; off <<= 1) {
        int t = (threadIdx.x >= off) ? s[threadIdx.x - off] : 0;
        __syncthreads();
        s[threadIdx.x] += t;
        __syncthreads();
    }
    int off0 = blockIdx.x ? part[blockIdx.x - 1] : 0;
    if (i < n) {
        int incl = s[threadIdx.x];
        int excl = off0 + incl - v;
        rp[i] = excl;
        cur[i] = excl;
        if (i == n - 1) rp[n] = off0 + incl;
    }
}

__global__ __launch_bounds__(256) void fill_k(const int* __restrict__ ei,
        int* __restrict__ cur, int* __restrict__ csr, int E, int N,
        int t0, int tcnt)
{
    int idx = blockIdx.x * 256 + threadIdx.x;
    if (idx >= tcnt * E) return;
    int lt = (idx >= E) ? 1 : 0;
    int j  = idx - lt * E;
    int tt = t0 + lt;
    int dst = ei[(size_t)tt * 2 * E + E + j];
    int src = ei[(size_t)tt * 2 * E + j];
    int p = atomicAdd(&cur[lt * N + dst], 1);
    csr[p] = src;
}

// ===========================================================================
// CSR gather: agg[i] = sum_{j in N(i)} h[j]  (RAW sums — BN affine is linear
// and folded into node_k via a*(h+S) + (1+deg)*b2)
// ===========================================================================
template<int D>
__global__ __launch_bounds__(576) void gather_k(const float* __restrict__ h,
        const int* __restrict__ rp, const int* __restrict__ csr,
        float* __restrict__ agg, int n)
{
    const int NPB = 576 / D;
    int g = blockIdx.x * NPB + threadIdx.x / D;
    int lane = threadIdx.x % D;
    if (g >= n) return;
    int lo = rp[g], hi = rp[g + 1];
    float a0 = 0.f, a1 = 0.f, a2 = 0.f, a3 = 0.f;
    int e = lo;
    for (; e + 3 < hi; e += 4) {
        int s0 = csr[e], s1 = csr[e + 1], s2 = csr[e + 2], s3 = csr[e + 3];
        a0 += h[(size_t)s0 * D + lane];
        a1 += h[(size_t)s1 * D + lane];
        a2 += h[(size_t)s2 * D + lane];
        a3 += h[(size_t)s3 * D + lane];
    }
    for (; e < hi; ++e) a0 += h[(size_t)csr[e] * D + lane];
    agg[(size_t)g * D + lane] = (a0 + a1) + (a2 + a3);
}

// ===========================================================================
// Node MLP, with BN-of-previous-layer folded in as a per-block prologue that
// reduces the previous conv's per-block stat rows (no bnred_k dispatch):
//   hin = a⊙(h_i + S_i) + (1+deg_i)·b2 ; y = relu(Wa hin+ba) ;
//   out = relu(Wb y+bb) ; write per-block BN stat row for THIS layer.
// h and z may alias (each thread touches only its own row).
// ===========================================================================
template<int DIN, bool AFF>
__global__ __launch_bounds__(256) void node_k(
    const float* h, const float* __restrict__ agg, const int* __restrict__ deg,
    const float* __restrict__ bsprev, int nbp,
    const float* __restrict__ bng, const float* __restrict__ bnb, float inv_n,
    const float* __restrict__ wa, const float* __restrict__ ba,
    const float* __restrict__ wb, const float* __restrict__ bb,
    float* z, float* __restrict__ bstats, int n)
{
    __shared__ float swa[DIM_ * DIN], sba[DIM_], swb[DIM_ * DIM_], sbb[DIM_];
    __shared__ float sstat[4][2 * DIM_];
    __shared__ float sred[2 * DIM_];
    __shared__ float sa[DIM_], sb2[DIM_];

    for (int i = threadIdx.x; i < DIM_ * DIN;  i += 256) swa[i] = wa[i];
    for (int i = threadIdx.x; i < DIM_ * DIM_; i += 256) swb[i] = wb[i];
    if (threadIdx.x < DIM_) { sba[threadIdx.x] = ba[threadIdx.x];
                              sbb[threadIdx.x] = bb[threadIdx.x]; }

    if constexpr (AFF) {
        int tid = threadIdx.x;
        if (tid < 2 * DIM_) {   // reduce prev-layer per-block stat rows
            float s0=0,s1=0,s2=0,s3=0,s4=0,s5=0,s6=0,s7=0;
            int i = 0;
            for (; i + 8 <= nbp; i += 8) {
                s0 += bsprev[(size_t)(i+0) * (2*DIM_) + tid];
                s1 += bsprev[(size_t)(i+1) * (2*DIM_) + tid];
                s2 += bsprev[(size_t)(i+2) * (2*DIM_) + tid];
                s3 += bsprev[(size_t)(i+3) * (2*DIM_) + tid];
                s4 += bsprev[(size_t)(i+4) * (2*DIM_) + tid];
                s5 += bsprev[(size_t)(i+5) * (2*DIM_) + tid];
                s6 += bsprev[(size_t)(i+6) * (2*DIM_) + tid];
                s7 += bsprev[(size_t)(i+7) * (2*DIM_) + tid];
            }
            for (; i < nbp; ++i) s0 += bsprev[(size_t)i * (2*DIM_) + tid];
            sred[tid] = ((s0+s1)+(s2+s3)) + ((s4+s5)+(s6+s7));
        }
    }
    __syncthreads();
    if constexpr (AFF) {
        if (threadIdx.x < DIM_) {
            float mean = sred[threadIdx.x] * inv_n;
            float var  = sred[DIM_ + threadIdx.x] * inv_n - mean * mean;
            float aa   = bng[threadIdx.x] / sqrtf(var + BN_EPS);
            sa[threadIdx.x]  = aa;
            sb2[threadIdx.x] = bnb[threadIdx.x] - aa * mean;
        }
        __syncthreads();
    }

    int node = blockIdx.x * 256 + threadIdx.x;
    bool active = node < n;

    float hin[DIN];
    if (active) {
        if constexpr (DIN == 36) {
            const float4* hr4 = reinterpret_cast<const float4*>(h   + (size_t)node * DIN);
            const float4* ar4 = reinterpret_cast<const float4*>(agg + (size_t)node * DIN);
            #pragma unroll
            for (int q = 0; q < 9; ++q) {
                float4 hv = hr4[q], av = ar4[q];
                hin[4*q+0] = hv.x + av.x; hin[4*q+1] = hv.y + av.y;
                hin[4*q+2] = hv.z + av.z; hin[4*q+3] = hv.w + av.w;
            }
        } else {
            const float2* hr2 = reinterpret_cast<const float2*>(h   + (size_t)node * DIN);
            const float2* ar2 = reinterpret_cast<const float2*>(agg + (size_t)node * DIN);
            #pragma unroll
            for (int q = 0; q < DIN / 2; ++q) {
                float2 hv = hr2[q], av = ar2[q];
                hin[2*q+0] = hv.x + av.x; hin[2*q+1] = hv.y + av.y;
            }
        }
        if constexpr (AFF) {
            float ds = 1.0f + (float)deg[node];
            #pragma unroll
            for (int k = 0; k < DIN; ++k)
                hin[k] = sa[k] * hin[k] + ds * sb2[k];
        }
    } else {
        #pragma unroll
        for (int k = 0; k < DIN; ++k) hin[k] = 0.f;
    }

    float y[DIM_];
    #pragma unroll
    for (int j = 0; j < DIM_; ++j) {
        float acc = sba[j];
        #pragma unroll
        for (int k = 0; k < DIN; ++k) acc = fmaf(swa[j * DIN + k], hin[k], acc);
        y[j] = fmaxf(acc, 0.f);
    }

    float out[DIM_];
    #pragma unroll
    for (int j = 0; j < DIM_; ++j) {
        float acc = sbb[j];
        #pragma unroll
        for (int k = 0; k < DIM_; ++k) acc = fmaf(swb[j * DIM_ + k], y[k], acc);
        float o = fmaxf(acc, 0.f);
        out[j] = active ? o : 0.f;
    }

    if (active) {
        float* zr = z + (size_t)node * DIM_;
        #pragma unroll
        for (int j = 0; j < DIM_ / 4; ++j) {
            float4 t; t.x = out[4*j]; t.y = out[4*j+1]; t.z = out[4*j+2]; t.w = out[4*j+3];
            reinterpret_cast<float4*>(zr)[j] = t;
        }
    }

    // wave shuffle reduce -> LDS -> one partial stat row per block
    int wid = threadIdx.x >> 6, lane = threadIdx.x & 63;
    #pragma unroll
    for (int j = 0; j < DIM_; ++j) {
        float s = out[j], sq = out[j] * out[j];
        for (int off = 32; off; off >>= 1) {
            s  += __shfl_down(s,  off);
            sq += __shfl_down(sq, off);
        }
        if (lane == 0) { sstat[wid][j] = s; sstat[wid][DIM_ + j] = sq; }
    }
    __syncthreads();
    if (threadIdx.x < 2 * DIM_) {
        float s = sstat[0][threadIdx.x] + sstat[1][threadIdx.x]
                + sstat[2][threadIdx.x] + sstat[3][threadIdx.x];
        bstats[(size_t)blockIdx.x * (2 * DIM_) + threadIdx.x] = s;
    }
}

// ===========================================================================
// Per-graph mean pool (batch sorted), with conv-3 BN folded in via the same
// per-block bstats-reduction prologue.
// ===========================================================================
__global__ __launch_bounds__(288) void pool_k(
    const float* __restrict__ z,
    const float* __restrict__ bsprev, int nbp,
    const float* __restrict__ bng, const float* __restrict__ bnb, float inv_n,
    const int* __restrict__ batch, float* __restrict__ emb, int col0, int n)
{
    __shared__ float sred[2 * DIM_];
    __shared__ float sa[DIM_], sb2[DIM_];
    __shared__ int slo, shi;

    int tid = threadIdx.x;
    if (tid < 2 * DIM_) {
        float s0=0,s1=0,s2=0,s3=0,s4=0,s5=0,s6=0,s7=0;
        int i = 0;
        for (; i + 8 <= nbp; i += 8) {
            s0 += bsprev[(size_t)(i+0) * (2*DIM_) + tid];
            s1 += bsprev[(size_t)(i+1) * (2*DIM_) + tid];
            s2 += bsprev[(size_t)(i+2) * (2*DIM_) + tid];
            s3 += bsprev[(size_t)(i+3) * (2*DIM_) + tid];
            s4 += bsprev[(size_t)(i+4) * (2*DIM_) + tid];
            s5 += bsprev[(size_t)(i+5) * (2*DIM_) + tid];
            s6 += bsprev[(size_t)(i+6) * (2*DIM_) + tid];
            s7 += bsprev[(size_t)(i+7) * (2*DIM_) + tid];
        }
        for (; i < nbp; ++i) s0 += bsprev[(size_t)i * (2*DIM_) + tid];
        sred[tid] = ((s0+s1)+(s2+s3)) + ((s4+s5)+(s6+s7));
    }
    int g = blockIdx.x;
    if (tid == 0) {
        int lo = 0, hi = n;
        while (lo < hi) { int m = (lo + hi) >> 1; if (batch[m] < g) lo = m + 1; else hi = m; }
        slo = lo;
        int lo2 = lo, hi2 = n;
        while (lo2 < hi2) { int m = (lo2 + hi2) >> 1; if (batch[m] < g + 1) lo2 = m + 1; else hi2 = m; }
        shi = lo2;
    }
    __syncthreads();
    if (tid < DIM_) {
        float mean = sred[tid] * inv_n;
        float var  = sred[DIM_ + tid] * inv_n - mean * mean;
        float aa   = bng[tid] / sqrtf(var + BN_EPS);
        sa[tid]  = aa;
        sb2[tid] = bnb[tid] - aa * mean;
    }
    __syncthreads();

    int lo = slo, hi = shi;
    int f = tid % DIM_, j = tid / DIM_;   // j in 0..7
    float acc = 0.f;
    for (int i = lo + j; i < hi; i += 8) acc += z[(size_t)i * DIM_ + f];
    __shared__ float spool[288];
    spool[tid] = acc;
    __syncthreads();
    if (tid < DIM_) {
        float s = 0.f;
        #pragma unroll
        for (int jj = 0; jj < 8; ++jj) s += spool[f + DIM_ * jj];
        int cnt = hi - lo;
        float val = 0.f;
        if (cnt > 0) val = sa[f] * (s / (float)cnt) + sb2[f];
        emb[(size_t)g * (T_ * DIM_) + col0 + f] = val;
    }
}

// ===========================================================================
// Head: 72 -> 54 relu -> 18 relu -> 1 sigmoid, one thread per graph
// ===========================================================================
__global__ __launch_bounds__(256) void head_k(
    const float* __restrict__ emb,
    const float* __restrict__ hw1, const float* __restrict__ hb1,
    const float* __restrict__ hw2, const float* __restrict__ hb2,
    const float* __restrict__ hw3, const float* __restrict__ hb3,
    float* __restrict__ out, int ng)
{
    const int EMB = T_ * DIM_;            // 72
    __shared__ float s1[LIN_ * EMB], sb1[LIN_], s2[OUT_ * LIN_], sb2[OUT_], s3[OUT_];
    __shared__ float sb3;
    for (int i = threadIdx.x; i < LIN_ * EMB;  i += 256) s1[i] = hw1[i];
    for (int i = threadIdx.x; i < OUT_ * LIN_; i += 256) s2[i] = hw2[i];
    if (threadIdx.x < LIN_) sb1[threadIdx.x] = hb1[threadIdx.x];
    if (threadIdx.x < OUT_) { sb2[threadIdx.x] = hb2[threadIdx.x];
                              s3[threadIdx.x]  = hw3[threadIdx.x]; }
    if (threadIdx.x == 0) sb3 = hb3[0];
    __syncthreads();

    int g = blockIdx.x * 256 + threadIdx.x;
    if (g >= ng) return;

    float e[EMB];
    #pragma unroll
    for (int k = 0; k < EMB; ++k) e[k] = emb[(size_t)g * EMB + k];

    float t1[LIN_];
    #pragma unroll
    for (int j = 0; j < LIN_; ++j) {
        float acc = sb1[j];
        #pragma unroll
        for (int k = 0; k < EMB; ++k) acc = fmaf(s1[j * EMB + k], e[k], acc);
        t1[j] = fmaxf(acc, 0.f);
    }
    float t2[OUT_];
    #pragma unroll
    for (int j = 0; j < OUT_; ++j) {
        float acc = sb2[j];
        #pragma unroll
        for (int k = 0; k < LIN_; ++k) acc = fmaf(s2[j * LIN_ + k], t1[k], acc);
        t2[j] = fmaxf(acc, 0.f);
    }
    float acc = sb3;
    #pragma unroll
    for (int k = 0; k < OUT_; ++k) acc = fmaf(s3[k], t2[k], acc);
    out[g] = 1.f / (1.f + expf(-acc));
}

// ===========================================================================
extern "C" void kernel_launch(void* const* d_in, const int* in_sizes, int n_in,
                              void* d_out, int out_size, void* d_ws, size_t ws_size,
                              hipStream_t stream)
{
    const float* x     = (const float*)d_in[0];
    const int*   ei    = (const int*)d_in[1];
    const int*   batch = (const int*)d_in[2];
    const float* wA[3] = {(const float*)d_in[3], (const float*)d_in[7], (const float*)d_in[11]};
    const float* bA[3] = {(const float*)d_in[4], (const float*)d_in[8], (const float*)d_in[12]};
    const float* wB[3] = {(const float*)d_in[5], (const float*)d_in[9], (const float*)d_in[13]};
    const float* bB[3] = {(const float*)d_in[6], (const float*)d_in[10], (const float*)d_in[14]};
    const float* bng = (const float*)d_in[15];
    const float* bnb = (const float*)d_in[16];
    const float* hw1 = (const float*)d_in[17];
    const float* hb1 = (const float*)d_in[18];
    const float* hw2 = (const float*)d_in[19];
    const float* hb2 = (const float*)d_in[20];
    const float* hw3 = (const float*)d_in[21];
    const float* hb3 = (const float*)d_in[22];

    const int N = in_sizes[2] / T_;           // nodes
    const int E = in_sizes[1] / (2 * T_);     // edges per transform
    const int G = out_size;                   // graphs
    const int gn = (N + 255) / 256;           // node_k blocks (stat rows)
    const float inv_n = 1.0f / (float)N;

    // ---- workspace layout (floats, then ints sized for tcnt transforms) ---
    const size_t bufN = (size_t)N * DIM_;
    char* ws = (char*)d_ws;
    float* agg  = (float*)ws;                             // N*36
    float* z    = agg + bufN;                             // N*36
    float* bsA  = z + bufN;                               // gn*72
    float* bsB  = bsA + (size_t)gn * 2 * DIM_;            // gn*72
    float* emb  = bsB + (size_t)gn * 2 * DIM_;            // G*72
    int*   ints = (int*)(emb + (size_t)G * T_ * DIM_);

    auto need = [&](int tc) -> size_t {
        size_t f = 2 * bufN + (size_t)2 * gn * 2 * DIM_ + (size_t)G * T_ * DIM_;
        size_t ii = (size_t)tc * N            // deg
                  + (size_t)tc * N + 1        // rp
                  + (size_t)tc * N            // cur
                  + (size_t)tc * E            // csr
                  + 1024;                     // part
        return f * sizeof(float) + ii * sizeof(int);
    };
    int tcnt = (need(2) <= ws_size) ? 2 : 1;  // combined build if ws allows
    // (need(1) matches R3's proven-fitting footprint)

    float* outp = (float*)d_out;

    auto build = [&](int t0, int tc, int* deg, int* rp, int* cur, int* csr, int* part) {
        int n2 = tc * N;
        int e2 = tc * E;
        int NB = (n2 + 255) / 256;
        hipMemsetAsync(deg, 0, (size_t)n2 * sizeof(int), stream);
        degcnt_k<<<(e2 + 255) / 256, 256, 0, stream>>>(ei, deg, E, N, t0, tc);
        partsum_k<<<NB, 256, 0, stream>>>(deg, part, n2);
        scanpart_k<<<1, 1024, 0, stream>>>(part, NB);
        scanchunk_k<<<NB, 256, 0, stream>>>(deg, part, rp, cur, n2);
        fill_k<<<(e2 + 255) / 256, 256, 0, stream>>>(ei, cur, csr, E, N, t0, tc);
    };

    int* deg  = ints;
    int* rp   = deg + (size_t)tcnt * N;
    int* cur  = rp + (size_t)tcnt * N + 1;
    int* csr  = cur + (size_t)tcnt * N;
    int* part = csr + (size_t)tcnt * E;

    if (tcnt == 2) build(0, 2, deg, rp, cur, csr, part);

    for (int t = 0; t < T_; ++t) {
        if (tcnt == 1) build(t, 1, deg, rp, cur, csr, part);
        int lt = (tcnt == 2) ? t : 0;
        const int*   rpt  = rp  + (size_t)lt * N;
        const int*   degt = deg + (size_t)lt * N;
        const float* xt   = x + (size_t)t * N * IN_;

        for (int c = 0; c < 3; ++c) {
            const float* bsprev = (c == 1) ? bsA : bsB;
            float*       bsout  = (c == 1) ? bsB : bsA;   // c0->A, c1->B, c2->A

            if (c == 0)
                gather_k<IN_><<<(N + 95) / 96, 576, 0, stream>>>(xt, rpt, csr, agg, N);
            else
                gather_k<DIM_><<<(N + 15) / 16, 576, 0, stream>>>(z, rpt, csr, agg, N);

            const float* wa = wA[c] + (size_t)t * DIM_ * ((c == 0) ? IN_ : DIM_);
            const float* ba = bA[c] + (size_t)t * DIM_;
            const float* wb = wB[c] + (size_t)t * DIM_ * DIM_;
            const float* bb = bB[c] + (size_t)t * DIM_;
            const float* gprev = bng + ((size_t)t * 3 + (c - 1)) * DIM_;  // c>0 only
            const float* bprev = bnb + ((size_t)t * 3 + (c - 1)) * DIM_;

            if (c == 0)
                node_k<IN_, false><<<gn, 256, 0, stream>>>(xt, agg, degt,
                        nullptr, 0, nullptr, nullptr, inv_n,
                        wa, ba, wb, bb, z, bsout, N);
            else
                node_k<DIM_, true><<<gn, 256, 0, stream>>>(z, agg, degt,
                        bsprev, gn, gprev, bprev, inv_n,
                        wa, ba, wb, bb, z, bsout, N);
        }
        pool_k<<<G, 288, 0, stream>>>(z, bsA, gn,
                bng + ((size_t)t * 3 + 2) * DIM_,
                bnb + ((size_t)t * 3 + 2) * DIM_, inv_n,
                batch + (size_t)t * N, emb, t * DIM_, N);
    }
    head_k<<<(G + 255) / 256, 256, 0, stream>>>(emb, hw1, hb1, hw2, hb2, hw3, hb3,
                                                outp, G);
}